// Round 9
// baseline (220.811 us; speedup 1.0000x reference)
//
#include <hip/hip_runtime.h>

#define N1 4096
#define N2 2048
#define PD 256
#define DZ 128
#define PD2 258
#define PD2P 264
#define FD 772
#define FDP 776
#define APN 272      // lmFT rows padded; row 258 = ones -> attr_sum
#define APLD 72
#define SPLITS 16
#define RLD 268      // full-K panel row stride (264 data + 4 pad; 6*row%32 spreads banks)
#define SLD 132      // scores_e panel row stride (128 data + 4 pad)

typedef short s8v __attribute__((ext_vector_type(8)));
typedef float f32x4 __attribute__((ext_vector_type(4)));

__device__ __forceinline__ short f2b(float f) {
    union { float f; unsigned u; } v; v.f = f;
    unsigned r = v.u + 0x7fffu + ((v.u >> 16) & 1u);
    return (short)(r >> 16);
}
__device__ __forceinline__ float sb2f(short s) {
    union { unsigned u; float f; } v;
    v.u = ((unsigned)(unsigned short)s) << 16;
    return v.f;
}

// ---------------------------------------------------------------- cvt_all
// blocks [0,256): 64x64 lmX transpose tiles -> lmFTb + lmXb + router partials
// blocks [256, ...): flat elementwise ranges
constexpr int Q0 = N2 * PD;              // tgX -> outF/finalFb/tgXb
constexpr int Q1 = Q0 + PD2 * PD2P;      // w1wb
constexpr int Q2 = Q1 + PD2 * PD2P;      // w2wb
constexpr int Q3 = Q2 + PD2 * PD2P;      // w1wtb (W1 transposed, bf16)
constexpr int Q4 = Q3 + DZ * FDP;        // pqwb
constexpr int Q5 = Q4 + 3 * DZ * PD;     // aqwb/akwb/pkwb
constexpr int Q6 = Q5 + 16 * N1;         // lmFT rows 256..271
constexpr int Q7 = Q6 + N1;              // v2b + rou0/rou1
constexpr int Q8 = Q7 + N2;              // Z zero
constexpr int Q9 = Q8 + N2 * 4;          // finalFb tail zero
constexpr int TB = 256;
constexpr int CVT_GRID = TB + (Q9 + 255) / 256;

__global__ __launch_bounds__(256) void cvt_all(
    const float* __restrict__ lmX, const float* __restrict__ lmY,
    const float* __restrict__ tgX,
    const float* __restrict__ aqw, const float* __restrict__ akw,
    const float* __restrict__ pkw, const float* __restrict__ pqw,
    const float* __restrict__ w1w, const float* __restrict__ w2w,
    const float* __restrict__ lmd, const float* __restrict__ tgd,
    const float* __restrict__ g1, const float* __restrict__ g2,
    const float* __restrict__ g3, const float* __restrict__ al,
    const float* __restrict__ be,
    const float* __restrict__ pvw, const float* __restrict__ pvb,
    short* __restrict__ w1wb, short* __restrict__ w2wb,
    short* __restrict__ w1wtb, short* __restrict__ pqwb,
    short* __restrict__ aqwb, short* __restrict__ akwb,
    short* __restrict__ pkwb, short* __restrict__ lmXb,
    short* __restrict__ tgXb, short* __restrict__ lmFTb,
    float* __restrict__ rou0, float* __restrict__ rou1,
    float* __restrict__ v2b, float* __restrict__ Z,
    short* __restrict__ finalFb, float* __restrict__ outF,
    float* __restrict__ r1part, float* __restrict__ r2part)
{
    __shared__ __align__(16) short T[64][72];
    __shared__ float dsc[64];
    __shared__ float sp1[4][64];
    __shared__ float sp2[4][64];
    const int tid = threadIdx.x;

    if (blockIdx.x < TB) {                       // ---- transpose tile
        const int rb = blockIdx.x >> 2, cb = blockIdx.x & 3;
        const int r0 = rb * 64, c0 = cb * 64;
        const int rr = tid >> 2, cg = tid & 3;
        const float* src = lmX + (size_t)(r0 + rr) * PD + c0 + cg * 16;
        f32x4 f0 = *(const f32x4*)(src);
        f32x4 f1 = *(const f32x4*)(src + 4);
        f32x4 f2v = *(const f32x4*)(src + 8);
        f32x4 f3v = *(const f32x4*)(src + 12);
        s8v h0, h1;
#pragma unroll
        for (int q = 0; q < 4; ++q) {
            h0[q] = f2b(f0[q]); h0[4 + q] = f2b(f1[q]);
            h1[q] = f2b(f2v[q]); h1[4 + q] = f2b(f3v[q]);
        }
        short* xb = lmXb + (size_t)(r0 + rr) * PD + c0 + cg * 16;
        *(s8v*)(xb) = h0; *(s8v*)(xb + 8) = h1;
        *(s8v*)(&T[rr][cg * 16]) = h0;
        *(s8v*)(&T[rr][cg * 16 + 8]) = h1;
        if (cg == 0) dsc[rr] = __expf(-g1[0] * (al[0] * lmd[r0 + rr] + be[0]));
        __syncthreads();
        {
            const int c = tid & 63, q = tid >> 6;
            float s1 = 0.f, s2 = 0.f;
#pragma unroll
            for (int k = 0; k < 16; ++k) {
                float x = sb2f(T[q * 16 + k][c]);
                s1 += x; s2 += dsc[q * 16 + k] * x;
            }
            sp1[q][c] = s1; sp2[q][c] = s2;
        }
        __syncthreads();
        if (tid < 64) {
            float S1 = sp1[0][tid] + sp1[1][tid] + sp1[2][tid] + sp1[3][tid];
            float S2 = sp2[0][tid] + sp2[1][tid] + sp2[2][tid] + sp2[3][tid];
            // rb-major layout: coalesced reduce in stage B
            r1part[(size_t)rb * 256 + c0 + tid] = S1;
            r2part[(size_t)rb * 256 + c0 + tid] = S2;
        }
        {
            const int c = tid >> 2, seg = tid & 3;
            s8v o0, o1;
#pragma unroll
            for (int k = 0; k < 8; ++k) {
                o0[k] = T[seg * 16 + k][c];
                o1[k] = T[seg * 16 + 8 + k][c];
            }
            short* dst = lmFTb + (size_t)(c0 + c) * N1 + r0 + seg * 16;
            *(s8v*)(dst) = o0; *(s8v*)(dst + 8) = o1;
        }
        return;
    }

    int i = (blockIdx.x - TB) * 256 + tid;       // ---- elementwise ranges
    if (i < Q0) { int r = i >> 8, c = i & 255;
                  float v = tgX[i]; short h = f2b(v);
                  outF[(size_t)r * FD + c] = v;
                  finalFb[(size_t)r * FDP + c] = h;
                  tgXb[i] = h; return; }
    if (i < Q1) { int j = i - Q0; int r = j / PD2P, c = j - r * PD2P;
                  w1wb[j] = (c < PD2) ? f2b(w1w[r * PD2 + c]) : (short)0; return; }
    if (i < Q2) { int j = i - Q1; int r = j / PD2P, c = j - r * PD2P;
                  w2wb[j] = (c < PD2) ? f2b(w2w[r * PD2 + c]) : (short)0; return; }
    if (i < Q3) { int j = i - Q2; int r = j / PD2P, c = j - r * PD2P;
                  // w1wtb[c1][k] = W1[k][c1]
                  w1wtb[j] = (c < PD2) ? f2b(w1w[c * PD2 + r]) : (short)0; return; }
    if (i < Q4) { int j = i - Q3; int r = j / FDP, c = j - r * FDP;
                  pqwb[j] = (c < FD) ? f2b(pqw[r * FD + c]) : (short)0; return; }
    if (i < Q5) { int j = i - Q4; int w = j >> 15, idx = j & 32767;
                  const float* s = (w == 0) ? aqw : (w == 1) ? akw : pkw;
                  short* d = (w == 0) ? aqwb : (w == 1) ? akwb : pkwb;
                  d[idx] = f2b(s[idx]); return; }
    if (i < Q6) { int j = i - Q5; int c = 256 + (j >> 12), r = j & (N1 - 1);
                  float v = 0.f;
                  if (c < PD2) v = lmY[2 * r + (c - 256)];
                  else if (c == PD2) v = 1.0f;         // ones col -> attr_sum
                  lmFTb[(size_t)c * N1 + r] = f2b(v); return; }
    if (i < Q7) { int j = i - Q6;   // j in [0,4096)
                  float a = al[0], b = be[0];
                  float y0 = lmY[2 * j], y1 = lmY[2 * j + 1];
                  v2b[2 * j]     = pvw[0] * y0 + pvw[1] * y1 + pvb[0];
                  v2b[2 * j + 1] = pvw[2] * y0 + pvw[3] * y1 + pvb[1];
                  if (j < N2) { float t = a * tgd[j] + b;
                                rou0[j] = __expf(-g2[0] * t);
                                rou1[j] = __expf(-g3[0] * t); }
                  return; }
    if (i < Q8) { Z[i - Q7] = 0.f; return; }
    if (i < Q9) { int j = i - Q8; int r = j >> 2;
                  finalFb[(size_t)r * FDP + FD + (j & 3)] = 0; return; }
}

// ---------------------------------------------------------------- kk + qb + Wc + router stage B
// block 0: router partial finalize; [1,257): kk; [257,321): qb; [321,346): Wc
// Full-K LDS staging: ONE barrier per block (was 16).
__global__ __launch_bounds__(256) void rkq_kernel(
    const short* __restrict__ lmXb, const short* __restrict__ tgXb,
    const short* __restrict__ aqwb, const short* __restrict__ akwb,
    const short* __restrict__ pkwb,
    const float* __restrict__ aqb, const float* __restrict__ akb,
    const float* __restrict__ pkb,
    const short* __restrict__ w2wb, const short* __restrict__ w1wtb,
    const float* __restrict__ r1part, const float* __restrict__ r2part,
    const float* __restrict__ lmY, const float* __restrict__ lmd,
    const float* __restrict__ g1, const float* __restrict__ al,
    const float* __restrict__ be,
    short* __restrict__ kk, short* __restrict__ qb, short* __restrict__ wcb,
    float* __restrict__ router0, float* __restrict__ rp0g)
{
    __shared__ __align__(16) short LDS[2 * 64 * RLD];   // 68.6 KB
    const int j = blockIdx.x, tid = threadIdx.x;

    if (j == 0) {                                  // ---- stage B: finalize router0 / rp0
        float* red = (float*)LDS;                  // 256 floats
        float S1 = 0.f, S2 = 0.f;
#pragma unroll 8
        for (int k = 0; k < 64; ++k) {             // coalesced: lane c reads row k
            S1 += r1part[(size_t)k * 256 + tid];
            S2 += r2part[(size_t)k * 256 + tid];
        }
        float a_ = al[0], b_ = be[0], gg = g1[0];
        float sd = 0.f, sdy0 = 0.f, sdy1 = 0.f, sy0 = 0.f, sy1 = 0.f;
#pragma unroll 4
        for (int rr_ = tid; rr_ < N1; rr_ += 256) {
            float d = __expf(-gg * (a_ * lmd[rr_] + b_));
            float y0v = lmY[2 * rr_], y1v = lmY[2 * rr_ + 1];
            sd += d; sdy0 += d * y0v; sdy1 += d * y1v; sy0 += y0v; sy1 += y1v;
        }
        float tot[5]; float in5[5] = {sd, sdy0, sdy1, sy0, sy1};
#pragma unroll
        for (int t = 0; t < 5; ++t) {
            __syncthreads();
            red[tid] = in5[t];
            __syncthreads();
            for (int o = 128; o > 0; o >>= 1) {
                if (tid < o) red[tid] += red[tid + o];
                __syncthreads();
            }
            tot[t] = red[0];
        }
        float invd = 1.f / (1.f + tot[0] + 1e-12f);
        {
            float r0v = S1 * (1.f / (float)N1);
            router0[tid] = r0v;
            rp0g[tid] = (S2 + r0v) * invd;
        }
        if (tid == 0) {
            float r0a = tot[3] * (1.f / (float)N1);
            float r0b = tot[4] * (1.f / (float)N1);
            router0[256] = r0a; router0[257] = r0b;
            rp0g[256] = (tot[1] + r0a) * invd;
            rp0g[257] = (tot[2] + r0b) * invd;
        }
        return;
    }

    short* Als = LDS;
    short* Bls = LDS + 64 * RLD;
    const int lane = tid & 63, wv = tid >> 6;
    const int wm = wv >> 1, wn = wv & 1;
    const int lm = lane & 15, lq = lane >> 4;
    const f32x4 zero4 = {0.f, 0.f, 0.f, 0.f};
    const s8v zero8 = {0, 0, 0, 0, 0, 0, 0, 0};
    f32x4 acc[2][2] = {{zero4, zero4}, {zero4, zero4}};

    if (j < 257) {                                 // kk tile (K=256)
        int jt = j - 1;
        int row0 = (jt >> 2) * 64, col0 = (jt & 3) * 64;
#pragma unroll
        for (int l = 0; l < 8; ++l) {
            int id = l * 256 + tid;                // 2048 = 64 rows x 32 groups
            int r2 = id >> 5, g = id & 31;
            *(s8v*)(Als + r2 * RLD + g * 8) =
                *(const s8v*)(lmXb + (size_t)(row0 + r2) * PD + g * 8);
            int c = col0 + r2;
            *(s8v*)(Bls + r2 * RLD + g * 8) = (c < 128)
                ? *(const s8v*)(akwb + (size_t)c * PD + g * 8)
                : *(const s8v*)(pkwb + (size_t)(c - 128) * PD + g * 8);
        }
        __syncthreads();
#pragma unroll
        for (int ks = 0; ks < 8; ++ks) {
            int off = ks * 32 + lq * 8;
            s8v af[2], bf[2];
#pragma unroll
            for (int mt = 0; mt < 2; ++mt)
                af[mt] = *(const s8v*)(Als + (wm * 32 + mt * 16 + lm) * RLD + off);
#pragma unroll
            for (int nt = 0; nt < 2; ++nt)
                bf[nt] = *(const s8v*)(Bls + (wn * 32 + nt * 16 + lm) * RLD + off);
#pragma unroll
            for (int mt = 0; mt < 2; ++mt)
#pragma unroll
                for (int nt = 0; nt < 2; ++nt)
                    acc[mt][nt] = __builtin_amdgcn_mfma_f32_16x16x32_bf16(
                        af[mt], bf[nt], acc[mt][nt], 0, 0, 0);
        }
#pragma unroll
        for (int mt = 0; mt < 2; ++mt)
#pragma unroll
            for (int nt = 0; nt < 2; ++nt) {
                int c = col0 + wn * 32 + nt * 16 + lm;
                float bv = (c < 128) ? akb[c] : pkb[c - 128];
#pragma unroll
                for (int i = 0; i < 4; ++i) {
                    int rr = row0 + wm * 32 + mt * 16 + lq * 4 + i;
                    kk[(size_t)rr * 256 + c] = f2b(acc[mt][nt][i] + bv);
                }
            }
    } else if (j < 321) {                          // qb tile (K=256)
        int jt = j - 257;
        int row0 = (jt >> 1) * 64, col0 = (jt & 1) * 64;
#pragma unroll
        for (int l = 0; l < 8; ++l) {
            int id = l * 256 + tid;
            int r2 = id >> 5, g = id & 31;
            *(s8v*)(Als + r2 * RLD + g * 8) =
                *(const s8v*)(tgXb + (size_t)(row0 + r2) * PD + g * 8);
            *(s8v*)(Bls + r2 * RLD + g * 8) =
                *(const s8v*)(aqwb + (size_t)(col0 + r2) * PD + g * 8);
        }
        __syncthreads();
#pragma unroll
        for (int ks = 0; ks < 8; ++ks) {
            int off = ks * 32 + lq * 8;
            s8v af[2], bf[2];
#pragma unroll
            for (int mt = 0; mt < 2; ++mt)
                af[mt] = *(const s8v*)(Als + (wm * 32 + mt * 16 + lm) * RLD + off);
#pragma unroll
            for (int nt = 0; nt < 2; ++nt)
                bf[nt] = *(const s8v*)(Bls + (wn * 32 + nt * 16 + lm) * RLD + off);
#pragma unroll
            for (int mt = 0; mt < 2; ++mt)
#pragma unroll
                for (int nt = 0; nt < 2; ++nt)
                    acc[mt][nt] = __builtin_amdgcn_mfma_f32_16x16x32_bf16(
                        af[mt], bf[nt], acc[mt][nt], 0, 0, 0);
        }
        const float INV_TEMP = 0.08838834764831845f;
#pragma unroll
        for (int mt = 0; mt < 2; ++mt)
#pragma unroll
            for (int nt = 0; nt < 2; ++nt) {
                int c = col0 + wn * 32 + nt * 16 + lm;
                float bv = aqb[c];
#pragma unroll
                for (int i = 0; i < 4; ++i) {
                    int rr = row0 + wm * 32 + mt * 16 + lq * 4 + i;
                    qb[(size_t)rr * DZ + c] = f2b(INV_TEMP * (acc[mt][nt][i] + bv));
                }
            }
    } else {                                       // Wc = W2 @ W1 tile (K=264)
        int jt = j - 321;
        int row0 = (jt / 5) * 64, col0 = (jt % 5) * 64;
#pragma unroll
        for (int l = 0; l < 9; ++l) {
            int id = l * 256 + tid;                // 64 rows x 33 groups = 2112
            if (id < 64 * 33) {
                int r2 = id / 33, g = id - r2 * 33;
                s8v va = zero8, vb = zero8;
                int c2 = row0 + r2;
                if (c2 < PD2) va = *(const s8v*)(w2wb + (size_t)c2 * PD2P + g * 8);
                int c1 = col0 + r2;
                if (c1 < PD2) vb = *(const s8v*)(w1wtb + (size_t)c1 * PD2P + g * 8);
                *(s8v*)(Als + r2 * RLD + g * 8) = va;
                *(s8v*)(Bls + r2 * RLD + g * 8) = vb;
            }
        }
        __syncthreads();
#pragma unroll
        for (int ks = 0; ks < 9; ++ks) {
            int off = ks * 32 + lq * 8;
            s8v af[2], bf[2];
            if (off < PD2P) {
#pragma unroll
                for (int mt = 0; mt < 2; ++mt)
                    af[mt] = *(const s8v*)(Als + (wm * 32 + mt * 16 + lm) * RLD + off);
#pragma unroll
                for (int nt = 0; nt < 2; ++nt)
                    bf[nt] = *(const s8v*)(Bls + (wn * 32 + nt * 16 + lm) * RLD + off);
            } else {
                af[0] = af[1] = bf[0] = bf[1] = zero8;
            }
#pragma unroll
            for (int mt = 0; mt < 2; ++mt)
#pragma unroll
                for (int nt = 0; nt < 2; ++nt)
                    acc[mt][nt] = __builtin_amdgcn_mfma_f32_16x16x32_bf16(
                        af[mt], bf[nt], acc[mt][nt], 0, 0, 0);
        }
#pragma unroll
        for (int mt = 0; mt < 2; ++mt)
#pragma unroll
            for (int nt = 0; nt < 2; ++nt) {
                int c = col0 + wn * 32 + nt * 16 + lm;
                if (c >= PD2P) continue;
#pragma unroll
                for (int i = 0; i < 4; ++i) {
                    int rr = row0 + wm * 32 + mt * 16 + lq * 4 + i;
                    if (rr < PD2) wcb[(size_t)rr * PD2P + c] = f2b(acc[mt][nt][i]);
                }
            }
    }
}

// ---------------------------------------------------------------- scores1 + exp (+stage C: router1)
// blocks [0,512): GEMM tiles (full-K staging, ONE barrier); [512,516): router1 dots
__global__ __launch_bounds__(256) void scores_e(
    const short* __restrict__ Qb, const short* __restrict__ Kk,
    short* __restrict__ E, float* __restrict__ Z,
    const float* __restrict__ w1w, const float* __restrict__ w1b,
    const float* __restrict__ rp0g, float* __restrict__ router1)
{
    const int j = blockIdx.x, tid = threadIdx.x;
    __shared__ __align__(16) short LDS[2 * 128 * SLD];   // 67.6 KB
    if (j >= 512) {                                // ---- stage C
        float* rp0s = (float*)LDS;                 // 258 floats
        for (int c = tid; c < PD2; c += 256) rp0s[c] = rp0g[c];
        __syncthreads();
        const int wv = tid >> 6, lane = tid & 63;
        int cstart = (j - 512) * 66;
        int cend = cstart + 66; if (cend > PD2) cend = PD2;
        for (int c = cstart + wv; c < cend; c += 4) {
            const float* wr = w1w + (size_t)c * PD2;
            float p = wr[lane] * rp0s[lane]
                    + wr[64 + lane] * rp0s[64 + lane]
                    + wr[128 + lane] * rp0s[128 + lane]
                    + wr[192 + lane] * rp0s[192 + lane];
            if (lane < 2) p += wr[256 + lane] * rp0s[256 + lane];
#pragma unroll
            for (int msk = 1; msk < 64; msk <<= 1) p += __shfl_xor(p, msk, 64);
            if (lane == 0) router1[c] = p + w1b[c];
        }
        return;
    }
    short* Als = LDS;
    short* Bls = LDS + 128 * SLD;
    const int lane = tid & 63, wv = tid >> 6;
    const int wm = wv >> 1, wn = wv & 1;
    const int lm = lane & 15, lq = lane >> 4;
    const int row0 = (j >> 5) * 128, col0 = (j & 31) * 128;
    const f32x4 zero4 = {0.f, 0.f, 0.f, 0.f};
    f32x4 acc[4][4];
#pragma unroll
    for (int mt = 0; mt < 4; ++mt)
#pragma unroll
        for (int nt = 0; nt < 4; ++nt) acc[mt][nt] = zero4;
#pragma unroll
    for (int l = 0; l < 8; ++l) {
        int id = l * 256 + tid;                    // 2048 = 128 rows x 16 groups
        int r = id >> 4, g = id & 15;
        *(s8v*)(Als + r * SLD + g * 8) = *(const s8v*)(Qb + (size_t)(row0 + r) * DZ + g * 8);
        *(s8v*)(Bls + r * SLD + g * 8) = *(const s8v*)(Kk + (size_t)(col0 + r) * 256 + g * 8);
    }
    __syncthreads();
#pragma unroll
    for (int ks = 0; ks < 4; ++ks) {
        int off = ks * 32 + lq * 8;
        s8v af[4], bf[4];
#pragma unroll
        for (int mt = 0; mt < 4; ++mt)
            af[mt] = *(const s8v*)(Als + (wm * 64 + mt * 16 + lm) * SLD + off);
#pragma unroll
        for (int nt = 0; nt < 4; ++nt)
            bf[nt] = *(const s8v*)(Bls + (wn * 64 + nt * 16 + lm) * SLD + off);
#pragma unroll
        for (int mt = 0; mt < 4; ++mt)
#pragma unroll
            for (int nt = 0; nt < 4; ++nt)
                acc[mt][nt] = __builtin_amdgcn_mfma_f32_16x16x32_bf16(
                    af[mt], bf[nt], acc[mt][nt], 0, 0, 0);
    }
#pragma unroll
    for (int mt = 0; mt < 4; ++mt)
#pragma unroll
        for (int i = 0; i < 4; ++i) {
            int r = row0 + wm * 64 + mt * 16 + lq * 4 + i;
            float rs = 0.f;
#pragma unroll
            for (int nt = 0; nt < 4; ++nt) {
                int c = col0 + wn * 64 + nt * 16 + lm;
                float e = __expf(acc[mt][nt][i]);
                E[(size_t)r * N1 + c] = f2b(e);
                rs += e;
            }
#pragma unroll
            for (int msk = 1; msk < 16; msk <<= 1) rs += __shfl_xor(rs, msk, 64);
            if (lm == 0) atomicAdd(&Z[r], rs);
        }
}

// ---------------------------------------------------------------- AP split-K (+stage D: rr2/u0)
// blocks [0,256): GEMM (128-row, 512 thr — R5-proven); [256,260): rr2/u0 wave dots
__global__ __launch_bounds__(512) void ap_gemm(const short* __restrict__ E,
                                               const float* __restrict__ Z,
                                               const short* __restrict__ lmFTb,
                                               short* __restrict__ part,
                                               const float* __restrict__ w2w,
                                               const float* __restrict__ w1b,
                                               const float* __restrict__ router1,
                                               float* __restrict__ rr2,
                                               float* __restrict__ u0)
{
    __shared__ __align__(16) short LDS[28800];     // 57.6 KB
    const int tid = threadIdx.x, bid = blockIdx.x;
    if (bid >= 256) {                              // ---- stage D
        float* r1s = (float*)LDS;                  // 258
        float* b1s = r1s + 260;                    // 258
        for (int c = tid; c < PD2; c += 512) { r1s[c] = router1[c]; b1s[c] = w1b[c]; }
        __syncthreads();
        const int wv8 = tid >> 6, lane = tid & 63;
        int cstart = (bid - 256) * 66;
        int cend = cstart + 66; if (cend > PD2) cend = PD2;
        for (int c = cstart + wv8; c < cend; c += 8) {
            const float* wr = w2w + (size_t)c * PD2;
            float w0 = wr[lane], w1v = wr[64 + lane], w2v = wr[128 + lane], w3 = wr[192 + lane];
            float pa = w0 * r1s[lane] + w1v * r1s[64 + lane]
                     + w2v * r1s[128 + lane] + w3 * r1s[192 + lane];
            float pb = w0 * b1s[lane] + w1v * b1s[64 + lane]
                     + w2v * b1s[128 + lane] + w3 * b1s[192 + lane];
            if (lane < 2) {
                float w4 = wr[256 + lane];
                pa += w4 * r1s[256 + lane]; pb += w4 * b1s[256 + lane];
            }
#pragma unroll
            for (int msk = 1; msk < 64; msk <<= 1) {
                pa += __shfl_xor(pa, msk, 64);
                pb += __shfl_xor(pb, msk, 64);
            }
            if (lane == 0) { rr2[c] = pa; u0[c] = pb; }
        }
        return;
    }
    const int lane = tid & 63, w8 = tid >> 6;
    const int lm = lane & 15, lq = lane >> 4;
    const int s = bid & 15, row0 = (bid >> 4) * 128;
    const int kbase = s * (N1 / SPLITS);
    short* Als = LDS;
    short* Bls = LDS + 128 * APLD;
    const f32x4 zero4 = {0.f, 0.f, 0.f, 0.f};
    f32x4 acc[17];
#pragma unroll
    for (int nt = 0; nt < 17; ++nt) acc[nt] = zero4;
    for (int it = 0; it < (N1 / SPLITS) / 64; ++it) {
        int k0 = kbase + it * 64;
#pragma unroll
        for (int l = 0; l < 2; ++l) {
            int id = l * 512 + tid;
            int r = id >> 3, gg = id & 7;
            s8v ev = *(const s8v*)(E + (size_t)(row0 + r) * N1 + k0 + gg * 8);
            float invZ = __builtin_amdgcn_rcpf(Z[row0 + r]);
            s8v av;
#pragma unroll
            for (int q = 0; q < 8; ++q)
                av[q] = f2b(__expf(sb2f(ev[q]) * invZ));
            *(s8v*)(Als + r * APLD + gg * 8) = av;
        }
#pragma unroll
        for (int l = 0; l < 5; ++l) {
            int id = l * 512 + tid;
            if (id < APN * 8) {
                int r = id >> 3, gg = id & 7;
                *(s8v*)(Bls + r * APLD + gg * 8) =
                    *(const s8v*)(lmFTb + (size_t)r * N1 + k0 + gg * 8);
            }
        }
        __syncthreads();
        s8v a0 = *(const s8v*)(Als + (w8 * 16 + lm) * APLD + lq * 8);
        s8v a1 = *(const s8v*)(Als + (w8 * 16 + lm) * APLD + 32 + lq * 8);
#pragma unroll
        for (int nt = 0; nt < 17; ++nt) {
            s8v b0 = *(const s8v*)(Bls + (nt * 16 + lm) * APLD + lq * 8);
            s8v b1 = *(const s8v*)(Bls + (nt * 16 + lm) * APLD + 32 + lq * 8);
            acc[nt] = __builtin_amdgcn_mfma_f32_16x16x32_bf16(a0, b0, acc[nt], 0, 0, 0);
            acc[nt] = __builtin_amdgcn_mfma_f32_16x16x32_bf16(a1, b1, acc[nt], 0, 0, 0);
        }
        __syncthreads();
    }
    short* op = part + (size_t)s * N2 * APN;
#pragma unroll
    for (int nt = 0; nt < 17; ++nt) {
        int c = nt * 16 + lm;
#pragma unroll
        for (int i = 0; i < 4; ++i) {
            int r = row0 + w8 * 16 + lq * 4 + i;
            op[(size_t)r * APN + c] = f2b(acc[nt][i]);
        }
    }
}

// ---------------------------------------------------------------- tgp0 reduce+fixup
__global__ __launch_bounds__(256) void fix_tgp0(const short* __restrict__ part,
                                                const float* __restrict__ tgX,
                                                const float* __restrict__ rou0,
                                                const float* __restrict__ router0,
                                                short* __restrict__ outb) {
    int r = blockIdx.x;
    int tid = threadIdx.x;
    __shared__ float sAsum;
    float s0 = 0.f, s1 = 0.f;
#pragma unroll
    for (int s = 0; s < SPLITS; ++s)
        s0 += sb2f(part[((size_t)s * N2 + r) * APN + tid]);
    if (tid < 8) {
#pragma unroll
        for (int s = 0; s < SPLITS; ++s)
            s1 += sb2f(part[((size_t)s * N2 + r) * APN + 256 + tid]);
    }
    if (tid == 2) sAsum = s1;   // col 258
    __syncthreads();
    float ro = rou0[r];
    float inv = 1.f / (1.f + sAsum + ro + 1e-12f);
    {
        float v = (s0 + tgX[(size_t)r * PD + tid] + ro * router0[tid]) * inv;
        outb[(size_t)r * PD2P + tid] = f2b(v);
    }
    if (tid < 8) {
        int c = 256 + tid;
        float v = 0.f;
        if (c < PD2) v = (s1 + ro * router0[c]) * inv;
        outb[(size_t)r * PD2P + c] = f2b(v);
    }
}

// ---------------------------------------------------------------- fused W1/W2 layer GEMM
// grid (10, 32): x<5 -> tf1 = tgp0@W1^T + b1 (cols 256..513)
//                x>=5 -> tf2 = (tgp0@Wc^T + u0 + rou1*rr2)/(1+rou1) + b2 (cols 514..771)
// Full-K staging: ONE barrier per block (was 18).
__global__ __launch_bounds__(256) void w12_gemm(
    const short* __restrict__ A, const short* __restrict__ B1,
    const short* __restrict__ B2,
    const float* __restrict__ b1, const float* __restrict__ b2,
    const float* __restrict__ rou1, const float* __restrict__ rr2,
    const float* __restrict__ u0,
    float* __restrict__ outF, short* __restrict__ finalFb)
{
    __shared__ __align__(16) short LDS[2 * 64 * RLD];   // 68.6 KB
    short* Als = LDS;
    short* Bls = LDS + 64 * RLD;
    const int tid = threadIdx.x;
    const int lane = tid & 63, wv = tid >> 6;
    const int wm = wv >> 1, wn = wv & 1;
    const int lm = lane & 15, lq = lane >> 4;
    const int bx = blockIdx.x;
    const int mode2 = bx >= 5;
    const int col0 = (mode2 ? bx - 5 : bx) * 64;
    const short* B = mode2 ? B2 : B1;
    const int row0 = blockIdx.y * 64;
    const f32x4 zero4 = {0.f, 0.f, 0.f, 0.f};
    f32x4 acc[2][2] = {{zero4, zero4}, {zero4, zero4}};
    const s8v zero8 = {0, 0, 0, 0, 0, 0, 0, 0};
#pragma unroll
    for (int l = 0; l < 9; ++l) {
        int id = l * 256 + tid;                    // 64 rows x 33 groups = 2112
        if (id < 64 * 33) {
            int r2 = id / 33, g = id - r2 * 33;
            *(s8v*)(Als + r2 * RLD + g * 8) =
                *(const s8v*)(A + (size_t)(row0 + r2) * PD2P + g * 8);
            s8v vb = zero8;
            int c1 = col0 + r2;
            if (c1 < PD2) vb = *(const s8v*)(B + (size_t)c1 * PD2P + g * 8);
            *(s8v*)(Bls + r2 * RLD + g * 8) = vb;
        }
    }
    __syncthreads();
#pragma unroll
    for (int ks = 0; ks < 9; ++ks) {
        int off = ks * 32 + lq * 8;
        s8v af[2], bf[2];
        if (off < PD2P) {
#pragma unroll
            for (int mt = 0; mt < 2; ++mt)
                af[mt] = *(const s8v*)(Als + (wm * 32 + mt * 16 + lm) * RLD + off);
#pragma unroll
            for (int nt = 0; nt < 2; ++nt)
                bf[nt] = *(const s8v*)(Bls + (wn * 32 + nt * 16 + lm) * RLD + off);
        } else {
            af[0] = af[1] = bf[0] = bf[1] = zero8;
        }
#pragma unroll
        for (int mt = 0; mt < 2; ++mt)
#pragma unroll
            for (int nt = 0; nt < 2; ++nt)
                acc[mt][nt] = __builtin_amdgcn_mfma_f32_16x16x32_bf16(
                    af[mt], bf[nt], acc[mt][nt], 0, 0, 0);
    }
#pragma unroll
    for (int mt = 0; mt < 2; ++mt)
#pragma unroll
        for (int nt = 0; nt < 2; ++nt) {
            int c = col0 + wn * 32 + nt * 16 + lm;
            if (c >= PD2) continue;
#pragma unroll
            for (int i = 0; i < 4; ++i) {
                int rr = row0 + wm * 32 + mt * 16 + lq * 4 + i;
                float v;
                int co;
                if (!mode2) {
                    v = acc[mt][nt][i] + b1[c];
                    co = 256 + c;
                } else {
                    float ro = rou1[rr];
                    float invd = 1.f / (1.f + ro + 1e-12f);
                    v = (acc[mt][nt][i] + u0[c] + ro * rr2[c]) * invd + b2[c];
                    co = 514 + c;
                }
                outF[(size_t)rr * FD + co] = v;
                finalFb[(size_t)rr * FDP + co] = f2b(v);
            }
        }
}

// ---------------------------------------------------------------- q2 projection (K=776)
__global__ __launch_bounds__(256) void q2_gemm(
    const short* __restrict__ A, const short* __restrict__ B,
    const float* __restrict__ bias, short* __restrict__ outB)
{
    __shared__ __align__(16) short LDS[5120];
    short* Als = LDS;
    short* Bls = LDS + 64 * 40;
    const int tid = threadIdx.x;
    const int lane = tid & 63, wv = tid >> 6;
    const int wm = wv >> 1, wn = wv & 1;
    const int lm = lane & 15, lq = lane >> 4;
    const int row0 = blockIdx.y * 64, col0 = blockIdx.x * 64;
    const f32x4 zero4 = {0.f, 0.f, 0.f, 0.f};
    f32x4 acc[2][2] = {{zero4, zero4}, {zero4, zero4}};
    const s8v zero8 = {0, 0, 0, 0, 0, 0, 0, 0};
    const int r = tid >> 2, cgp = tid & 3;
    for (int k0 = 0; k0 < FDP; k0 += 32) {
        int gk = k0 + cgp * 8;
        s8v va = zero8, vb = zero8;
        if (gk < FDP) {
            va = *(const s8v*)(A + (size_t)(row0 + r) * FDP + gk);
            vb = *(const s8v*)(B + (size_t)(col0 + r) * FDP + gk);
        }
        *(s8v*)(Als + r * 40 + cgp * 8) = va;
        *(s8v*)(Bls + r * 40 + cgp * 8) = vb;
        __syncthreads();
        s8v af[2], bf[2];
#pragma unroll
        for (int mt = 0; mt < 2; ++mt)
            af[mt] = *(const s8v*)(Als + (wm * 32 + mt * 16 + lm) * 40 + lq * 8);
#pragma unroll
        for (int nt = 0; nt < 2; ++nt)
            bf[nt] = *(const s8v*)(Bls + (wn * 32 + nt * 16 + lm) * 40 + lq * 8);
#pragma unroll
        for (int mt = 0; mt < 2; ++mt)
#pragma unroll
            for (int nt = 0; nt < 2; ++nt)
                acc[mt][nt] = __builtin_amdgcn_mfma_f32_16x16x32_bf16(
                    af[mt], bf[nt], acc[mt][nt], 0, 0, 0);
        __syncthreads();
    }
    const float INV_TEMP = 0.08838834764831845f;
#pragma unroll
    for (int mt = 0; mt < 2; ++mt)
#pragma unroll
        for (int nt = 0; nt < 2; ++nt) {
            int c = col0 + wn * 32 + nt * 16 + lm;
            float bv = bias[c];
#pragma unroll
            for (int i = 0; i < 4; ++i) {
                int rr = row0 + wm * 32 + mt * 16 + lq * 4 + i;
                outB[(size_t)rr * DZ + c] = f2b(INV_TEMP * (acc[mt][nt][i] + bv));
            }
        }
}

// ---------------------------------------------------------------- attention 2
// 512 blocks: chunk (16 x 256 cols) x rowblock (32 x 64 rows).
// R5-proven: LDS-staged K, per-lane accumulation across tiles, single
// end-of-kernel butterfly, plain part2 stores + separate combine.
__global__ __launch_bounds__(256) void attn2_flash(
    const short* __restrict__ Q, const short* __restrict__ Kk,
    const float* __restrict__ V, float* __restrict__ part2)
{
    __shared__ __align__(16) short Qls[64 * 136];
    __shared__ __align__(16) short Kls[64 * 136];
    __shared__ float Vls[128];
    const int tid = threadIdx.x;
    const int lane = tid & 63, wv = tid >> 6;
    const int lm = lane & 15, lq = lane >> 4;
    const int chunk = blockIdx.x & 15, row0 = (blockIdx.x >> 4) * 64;
    const f32x4 zero4 = {0.f, 0.f, 0.f, 0.f};
#pragma unroll
    for (int l = 0; l < 4; ++l) {
        int id = l * 256 + tid;
        int r = id >> 4, g = id & 15;
        *(s8v*)(Qls + r * 136 + g * 8) = *(const s8v*)(Q + (size_t)(row0 + r) * DZ + g * 8);
    }
    __syncthreads();
    s8v af[4];
#pragma unroll
    for (int ks = 0; ks < 4; ++ks)
        af[ks] = *(const s8v*)(Qls + (wv * 16 + lm) * 136 + ks * 32 + lq * 8);
    float z[4] = {0.f, 0.f, 0.f, 0.f};
    float y0[4] = {0.f, 0.f, 0.f, 0.f};
    float y1[4] = {0.f, 0.f, 0.f, 0.f};
    for (int t = 0; t < 4; ++t) {
        int col0 = chunk * 256 + t * 64;
        __syncthreads();
#pragma unroll
        for (int l = 0; l < 4; ++l) {
            int id = l * 256 + tid;
            int r = id >> 4, g = id & 15;
            *(s8v*)(Kls + r * 136 + g * 8) =
                *(const s8v*)(Kk + (size_t)(col0 + r) * 256 + 128 + g * 8);
        }
        if (tid < 128) Vls[tid] = V[col0 * 2 + tid];
        __syncthreads();
        f32x4 acc[4];
#pragma unroll
        for (int nt = 0; nt < 4; ++nt) acc[nt] = zero4;
#pragma unroll
        for (int nt = 0; nt < 4; ++nt)
#pragma unroll
            for (int ks = 0; ks < 4; ++ks) {
                s8v bf = *(const s8v*)(Kls + (nt * 16 + lm) * 136 + ks * 32 + lq * 8);
                acc[nt] = __builtin_amdgcn_mfma_f32_16x16x32_bf16(af[ks], bf, acc[nt], 0, 0, 0);
            }
        float v0[4], v1[4];
#pragma unroll
        for (int nt = 0; nt < 4; ++nt) {
            v0[nt] = Vls[(nt * 16 + lm) * 2];
            v1[nt] = Vls[(nt * 16 + lm) * 2 + 1];
        }
        // per-lane accumulation: NO cross-lane ops inside the tile loop
#pragma unroll
        for (int i = 0; i < 4; ++i) {
            float e0 = __expf(acc[0][i]), e1 = __expf(acc[1][i]);
            float e2 = __expf(acc[2][i]), e3 = __expf(acc[3][i]);
            z[i]  += e0 + e1 + e2 + e3;
            y0[i] += e0 * v0[0] + e1 * v0[1] + e2 * v0[2] + e3 * v0[3];
            y1[i] += e0 * v1[0] + e1 * v1[1] + e2 * v1[2] + e3 * v1[3];
        }
    }
    // single end-of-kernel butterfly over the 16 column-lanes
#pragma unroll
    for (int i = 0; i < 4; ++i) {
#pragma unroll
        for (int msk = 1; msk < 16; msk <<= 1) {
            z[i]  += __shfl_xor(z[i], msk, 64);
            y0[i] += __shfl_xor(y0[i], msk, 64);
            y1[i] += __shfl_xor(y1[i], msk, 64);
        }
    }
    if (lm == 0) {
#pragma unroll
        for (int i = 0; i < 4; ++i) {
            int r = row0 + wv * 16 + lq * 4 + i;
            float* pp = part2 + ((size_t)r * 16 + chunk) * 4;
            pp[0] = z[i]; pp[1] = y0[i]; pp[2] = y1[i];
        }
    }
}

__global__ void attn2_combine(const float* __restrict__ part2, float* __restrict__ out) {
    int r = blockIdx.x * 256 + threadIdx.x;
    if (r >= N2) return;
    const float* pp = part2 + (size_t)r * 64;
    float Zt = 0.f, Y0 = 0.f, Y1 = 0.f;
#pragma unroll
    for (int c = 0; c < 16; ++c) {
        Zt += pp[c * 4]; Y0 += pp[c * 4 + 1]; Y1 += pp[c * 4 + 2];
    }
    out[2 * r] = Y0 / Zt;
    out[2 * r + 1] = Y1 / Zt;
}

// ---------------------------------------------------------------- launch
extern "C" void kernel_launch(void* const* d_in, const int* in_sizes, int n_in,
                              void* d_out, int out_size, void* d_ws, size_t ws_size,
                              hipStream_t stream) {
    const float* lm_X = (const float*)d_in[0];
    const float* lm_Y = (const float*)d_in[1];
    const float* tg_X = (const float*)d_in[2];
    const float* lm_delay = (const float*)d_in[4];
    const float* tg_delay = (const float*)d_in[5];
    const float* aq_w = (const float*)d_in[6];
    const float* aq_b = (const float*)d_in[7];
    const float* ak_w = (const float*)d_in[8];
    const float* ak_b = (const float*)d_in[9];
    const float* w1_w = (const float*)d_in[10];
    const float* w1_b = (const float*)d_in[11];
    const float* w2_w = (const float*)d_in[12];
    const float* w2_b = (const float*)d_in[13];
    const float* pq_w = (const float*)d_in[14];
    const float* pq_b = (const float*)d_in[15];
    const float* pk_w = (const float*)d_in[16];
    const float* pk_b = (const float*)d_in[17];
    const float* pv_w = (const float*)d_in[18];
    const float* pv_b = (const float*)d_in[19];
    const float* g1 = (const float*)d_in[20];
    const float* g2 = (const float*)d_in[21];
    const float* g3 = (const float*)d_in[22];
    const float* al = (const float*)d_in[23];
    const float* be = (const float*)d_in[24];

    float* out = (float*)d_out;
    float* outF = out + (size_t)N2 * 2;

    char* base = (char*)d_ws;
    size_t off = 0;
    auto allocF = [&](size_t n) -> float* {
        float* q = (float*)(base + off);
        off += (n * 4 + 255) / 256 * 256;
        return q;
    };
    auto allocS = [&](size_t n) -> short* {
        short* q = (short*)(base + off);
        off += (n * 2 + 255) / 256 * 256;
        return q;
    };

    short* E        = allocS((size_t)N2 * N1);
    short* appart   = allocS((size_t)SPLITS * N2 * APN);
    short* lmFTb    = allocS((size_t)APN * N1);
    short* lmXb     = allocS((size_t)N1 * PD);
    short* tgXb     = allocS((size_t)N2 * PD);
    short* qbuf     = allocS((size_t)N2 * DZ);
    short* kk       = allocS((size_t)N1 * 256);
    short* q2       = allocS((size_t)N2 * DZ);
    short* tgp0b    = allocS((size_t)N2 * PD2P);
    short* finalFb  = allocS((size_t)N2 * FDP);
    short* w1wb     = allocS((size_t)PD2 * PD2P);
    short* w2wb     = allocS((size_t)PD2 * PD2P);
    short* w1wtb    = allocS((size_t)PD2 * PD2P);
    short* wcb      = allocS((size_t)PD2 * PD2P);
    short* pqwb     = allocS((size_t)DZ * FDP);
    short* aqwb     = allocS((size_t)DZ * PD);
    short* akwb     = allocS((size_t)DZ * PD);
    short* pkwb     = allocS((size_t)DZ * PD);
    float* v2b      = allocF((size_t)N1 * 2);
    float* part2    = allocF((size_t)N2 * 64);
    float* Zbuf     = allocF(N2);
    float* router0  = allocF(PD2);
    float* rp0g     = allocF(PD2);
    float* router1  = allocF(PD2);
    float* rr2v     = allocF(PD2);
    float* u0v      = allocF(PD2);
    float* r1part   = allocF(64 * 256);
    float* r2part   = allocF(64 * 256);
    float* rou0     = allocF(N2);
    float* rou1     = allocF(N2);

    // 1. transpose + conversions + zero-fills (+ router partial sums)
    hipLaunchKernelGGL(cvt_all, dim3(CVT_GRID), dim3(256), 0, stream,
                       lm_X, lm_Y, tg_X, aq_w, ak_w, pk_w, pq_w, w1_w, w2_w,
                       lm_delay, tg_delay, g1, g2, g3, al, be, pv_w, pv_b,
                       w1wb, w2wb, w1wtb, pqwb, aqwb, akwb, pkwb,
                       lmXb, tgXb, lmFTb, rou0, rou1, v2b, Zbuf,
                       finalFb, outF, r1part, r2part);
    // 2. stage B (block 0) + kk + qb + Wc (full-K staging, 1 barrier)
    hipLaunchKernelGGL(rkq_kernel, dim3(346), dim3(256), 0, stream,
                       lmXb, tgXb, aqwb, akwb, pkwb, aq_b, ak_b, pk_b,
                       w2wb, w1wtb, r1part, r2part, lm_Y, lm_delay,
                       g1, al, be, kk, qbuf, wcb, router0, rp0g);
    // 3. E = exp(scores), Z rowsums (full-K staging; +stage C router1, 4 blocks)
    hipLaunchKernelGGL(scores_e, dim3(516), dim3(256), 0, stream,
                       qbuf, kk, E, Zbuf, w1_w, w1_b, rp0g, router1);
    // 4. AP partials, 128-row tiles (+stage D: rr2/u0, 4 blocks)
    hipLaunchKernelGGL(ap_gemm, dim3(260), dim3(512), 0, stream,
                       E, Zbuf, lmFTb, appart, w2_w, w1_b, router1, rr2v, u0v);
    // 5. tgp0
    hipLaunchKernelGGL(fix_tgp0, dim3(N2), dim3(256), 0, stream,
                       appart, tg_X, rou0, router0, tgp0b);
    // 6. tf1 + tf2 in parallel (full-K staging, 1 barrier)
    hipLaunchKernelGGL(w12_gemm, dim3(10, 32), dim3(256), 0, stream,
                       tgp0b, w1wb, wcb, w1_b, w2_b, rou1, rr2v, u0v,
                       outF, finalFb);
    // 7. q2
    hipLaunchKernelGGL(q2_gemm, dim3(2, 32), dim3(256), 0, stream,
                       finalFb, pqwb, pq_b, q2);
    // 8-9. attention 2 (R5 LDS-staged) + combine (no atomics)
    hipLaunchKernelGGL(attn2_flash, dim3(512), dim3(256), 0, stream,
                       q2, kk, v2b, part2);
    hipLaunchKernelGGL(attn2_combine, dim3(8), dim3(256), 0, stream, part2, out);
}

// Round 10
// 202.924 us; speedup vs baseline: 1.0881x; 1.0881x over previous
//
#include <hip/hip_runtime.h>

#define N1 4096
#define N2 2048
#define PD 256
#define DZ 128
#define PD2 258
#define PD2P 264
#define FD 772
#define FDP 776
#define APN 272      // lmFT rows padded; row 258 = ones -> attr_sum
#define APLD 72
#define SPLITS 16

typedef short s8v __attribute__((ext_vector_type(8)));
typedef float f32x4 __attribute__((ext_vector_type(4)));

__device__ __forceinline__ short f2b(float f) {
    union { float f; unsigned u; } v; v.f = f;
    unsigned r = v.u + 0x7fffu + ((v.u >> 16) & 1u);
    return (short)(r >> 16);
}
__device__ __forceinline__ float sb2f(short s) {
    union { unsigned u; float f; } v;
    v.u = ((unsigned)(unsigned short)s) << 16;
    return v.f;
}

// ---------------------------------------------------------------- cvt_all
// blocks [0,256): 64x64 lmX transpose tiles -> lmFTb + lmXb + router partials
// blocks [256, ...): flat elementwise ranges
constexpr int Q0 = N2 * PD;              // tgX -> outF/finalFb/tgXb
constexpr int Q1 = Q0 + PD2 * PD2P;      // w1wb
constexpr int Q2 = Q1 + PD2 * PD2P;      // w2wb
constexpr int Q3 = Q2 + PD2 * PD2P;      // w1wtb (W1 transposed, bf16)
constexpr int Q4 = Q3 + DZ * FDP;        // pqwb
constexpr int Q5 = Q4 + 3 * DZ * PD;     // aqwb/akwb/pkwb
constexpr int Q6 = Q5 + 16 * N1;         // lmFT rows 256..271
constexpr int Q7 = Q6 + N1;              // v2b + rou0/rou1
constexpr int Q8 = Q7 + N2;              // Z zero
constexpr int Q9 = Q8 + N2 * 4;          // finalFb tail zero
constexpr int TB = 256;
constexpr int CVT_GRID = TB + (Q9 + 255) / 256;

__global__ __launch_bounds__(256) void cvt_all(
    const float* __restrict__ lmX, const float* __restrict__ lmY,
    const float* __restrict__ tgX,
    const float* __restrict__ aqw, const float* __restrict__ akw,
    const float* __restrict__ pkw, const float* __restrict__ pqw,
    const float* __restrict__ w1w, const float* __restrict__ w2w,
    const float* __restrict__ lmd, const float* __restrict__ tgd,
    const float* __restrict__ g1, const float* __restrict__ g2,
    const float* __restrict__ g3, const float* __restrict__ al,
    const float* __restrict__ be,
    const float* __restrict__ pvw, const float* __restrict__ pvb,
    short* __restrict__ w1wb, short* __restrict__ w2wb,
    short* __restrict__ w1wtb, short* __restrict__ pqwb,
    short* __restrict__ aqwb, short* __restrict__ akwb,
    short* __restrict__ pkwb, short* __restrict__ lmXb,
    short* __restrict__ tgXb, short* __restrict__ lmFTb,
    float* __restrict__ rou0, float* __restrict__ rou1,
    float* __restrict__ v2b, float* __restrict__ Z,
    short* __restrict__ finalFb, float* __restrict__ outF,
    float* __restrict__ r1part, float* __restrict__ r2part)
{
    __shared__ __align__(16) short T[64][72];
    __shared__ float dsc[64];
    __shared__ float sp1[4][64];
    __shared__ float sp2[4][64];
    const int tid = threadIdx.x;

    if (blockIdx.x < TB) {                       // ---- transpose tile
        const int rb = blockIdx.x >> 2, cb = blockIdx.x & 3;
        const int r0 = rb * 64, c0 = cb * 64;
        const int rr = tid >> 2, cg = tid & 3;
        const float* src = lmX + (size_t)(r0 + rr) * PD + c0 + cg * 16;
        f32x4 f0 = *(const f32x4*)(src);
        f32x4 f1 = *(const f32x4*)(src + 4);
        f32x4 f2v = *(const f32x4*)(src + 8);
        f32x4 f3v = *(const f32x4*)(src + 12);
        s8v h0, h1;
#pragma unroll
        for (int q = 0; q < 4; ++q) {
            h0[q] = f2b(f0[q]); h0[4 + q] = f2b(f1[q]);
            h1[q] = f2b(f2v[q]); h1[4 + q] = f2b(f3v[q]);
        }
        short* xb = lmXb + (size_t)(r0 + rr) * PD + c0 + cg * 16;
        *(s8v*)(xb) = h0; *(s8v*)(xb + 8) = h1;
        *(s8v*)(&T[rr][cg * 16]) = h0;
        *(s8v*)(&T[rr][cg * 16 + 8]) = h1;
        if (cg == 0) dsc[rr] = __expf(-g1[0] * (al[0] * lmd[r0 + rr] + be[0]));
        __syncthreads();
        {
            const int c = tid & 63, q = tid >> 6;
            float s1 = 0.f, s2 = 0.f;
#pragma unroll
            for (int k = 0; k < 16; ++k) {
                float x = sb2f(T[q * 16 + k][c]);
                s1 += x; s2 += dsc[q * 16 + k] * x;
            }
            sp1[q][c] = s1; sp2[q][c] = s2;
        }
        __syncthreads();
        if (tid < 64) {
            float S1 = sp1[0][tid] + sp1[1][tid] + sp1[2][tid] + sp1[3][tid];
            float S2 = sp2[0][tid] + sp2[1][tid] + sp2[2][tid] + sp2[3][tid];
            // rb-major layout: coalesced reduce in stage B
            r1part[(size_t)rb * 256 + c0 + tid] = S1;
            r2part[(size_t)rb * 256 + c0 + tid] = S2;
        }
        {
            const int c = tid >> 2, seg = tid & 3;
            s8v o0, o1;
#pragma unroll
            for (int k = 0; k < 8; ++k) {
                o0[k] = T[seg * 16 + k][c];
                o1[k] = T[seg * 16 + 8 + k][c];
            }
            short* dst = lmFTb + (size_t)(c0 + c) * N1 + r0 + seg * 16;
            *(s8v*)(dst) = o0; *(s8v*)(dst + 8) = o1;
        }
        return;
    }

    int i = (blockIdx.x - TB) * 256 + tid;       // ---- elementwise ranges
    if (i < Q0) { int r = i >> 8, c = i & 255;
                  float v = tgX[i]; short h = f2b(v);
                  outF[(size_t)r * FD + c] = v;
                  finalFb[(size_t)r * FDP + c] = h;
                  tgXb[i] = h; return; }
    if (i < Q1) { int j = i - Q0; int r = j / PD2P, c = j - r * PD2P;
                  w1wb[j] = (c < PD2) ? f2b(w1w[r * PD2 + c]) : (short)0; return; }
    if (i < Q2) { int j = i - Q1; int r = j / PD2P, c = j - r * PD2P;
                  w2wb[j] = (c < PD2) ? f2b(w2w[r * PD2 + c]) : (short)0; return; }
    if (i < Q3) { int j = i - Q2; int r = j / PD2P, c = j - r * PD2P;
                  // w1wtb[c1][k] = W1[k][c1]
                  w1wtb[j] = (c < PD2) ? f2b(w1w[c * PD2 + r]) : (short)0; return; }
    if (i < Q4) { int j = i - Q3; int r = j / FDP, c = j - r * FDP;
                  pqwb[j] = (c < FD) ? f2b(pqw[r * FD + c]) : (short)0; return; }
    if (i < Q5) { int j = i - Q4; int w = j >> 15, idx = j & 32767;
                  const float* s = (w == 0) ? aqw : (w == 1) ? akw : pkw;
                  short* d = (w == 0) ? aqwb : (w == 1) ? akwb : pkwb;
                  d[idx] = f2b(s[idx]); return; }
    if (i < Q6) { int j = i - Q5; int c = 256 + (j >> 12), r = j & (N1 - 1);
                  float v = 0.f;
                  if (c < PD2) v = lmY[2 * r + (c - 256)];
                  else if (c == PD2) v = 1.0f;         // ones col -> attr_sum
                  lmFTb[(size_t)c * N1 + r] = f2b(v); return; }
    if (i < Q7) { int j = i - Q6;   // j in [0,4096)
                  float a = al[0], b = be[0];
                  float y0 = lmY[2 * j], y1 = lmY[2 * j + 1];
                  v2b[2 * j]     = pvw[0] * y0 + pvw[1] * y1 + pvb[0];
                  v2b[2 * j + 1] = pvw[2] * y0 + pvw[3] * y1 + pvb[1];
                  if (j < N2) { float t = a * tgd[j] + b;
                                rou0[j] = __expf(-g2[0] * t);
                                rou1[j] = __expf(-g3[0] * t); }
                  return; }
    if (i < Q8) { Z[i - Q7] = 0.f; return; }
    if (i < Q9) { int j = i - Q8; int r = j >> 2;
                  finalFb[(size_t)r * FDP + FD + (j & 3)] = 0; return; }
}

// ---------------------------------------------------------------- kk + qb + Wc + router stage B
// block 0: router partial finalize; [1,257): kk; [257,321): qb; [321,346): Wc
__global__ __launch_bounds__(256) void rkq_kernel(
    const short* __restrict__ lmXb, const short* __restrict__ tgXb,
    const short* __restrict__ aqwb, const short* __restrict__ akwb,
    const short* __restrict__ pkwb,
    const float* __restrict__ aqb, const float* __restrict__ akb,
    const float* __restrict__ pkb,
    const short* __restrict__ w2wb, const short* __restrict__ w1wtb,
    const float* __restrict__ r1part, const float* __restrict__ r2part,
    const float* __restrict__ lmY, const float* __restrict__ lmd,
    const float* __restrict__ g1, const float* __restrict__ al,
    const float* __restrict__ be,
    short* __restrict__ kk, short* __restrict__ qb, short* __restrict__ wcb,
    float* __restrict__ router0, float* __restrict__ rp0g)
{
    __shared__ __align__(16) short LDS[5120];
    const int j = blockIdx.x, tid = threadIdx.x;

    if (j == 0) {                                  // ---- stage B: finalize router0 / rp0
        float* red = (float*)LDS;                  // 256 floats
        float S1 = 0.f, S2 = 0.f;
#pragma unroll 8
        for (int k = 0; k < 64; ++k) {             // coalesced: lane c reads row k
            S1 += r1part[(size_t)k * 256 + tid];
            S2 += r2part[(size_t)k * 256 + tid];
        }
        float a_ = al[0], b_ = be[0], gg = g1[0];
        float sd = 0.f, sdy0 = 0.f, sdy1 = 0.f, sy0 = 0.f, sy1 = 0.f;
#pragma unroll 4
        for (int rr_ = tid; rr_ < N1; rr_ += 256) {
            float d = __expf(-gg * (a_ * lmd[rr_] + b_));
            float y0v = lmY[2 * rr_], y1v = lmY[2 * rr_ + 1];
            sd += d; sdy0 += d * y0v; sdy1 += d * y1v; sy0 += y0v; sy1 += y1v;
        }
        float tot[5]; float in5[5] = {sd, sdy0, sdy1, sy0, sy1};
#pragma unroll
        for (int t = 0; t < 5; ++t) {
            __syncthreads();
            red[tid] = in5[t];
            __syncthreads();
            for (int o = 128; o > 0; o >>= 1) {
                if (tid < o) red[tid] += red[tid + o];
                __syncthreads();
            }
            tot[t] = red[0];
        }
        float invd = 1.f / (1.f + tot[0] + 1e-12f);
        {
            float r0v = S1 * (1.f / (float)N1);
            router0[tid] = r0v;
            rp0g[tid] = (S2 + r0v) * invd;
        }
        if (tid == 0) {
            float r0a = tot[3] * (1.f / (float)N1);
            float r0b = tot[4] * (1.f / (float)N1);
            router0[256] = r0a; router0[257] = r0b;
            rp0g[256] = (tot[1] + r0a) * invd;
            rp0g[257] = (tot[2] + r0b) * invd;
        }
        return;
    }

    short* Als = LDS;
    short* Bls = LDS + 64 * 40;
    const int lane = tid & 63, wv = tid >> 6;
    const int wm = wv >> 1, wn = wv & 1;
    const int lm = lane & 15, lq = lane >> 4;
    const f32x4 zero4 = {0.f, 0.f, 0.f, 0.f};
    const s8v zero8 = {0, 0, 0, 0, 0, 0, 0, 0};
    f32x4 acc[2][2] = {{zero4, zero4}, {zero4, zero4}};
    const int r = tid >> 2, cgp = tid & 3;

    if (j < 257) {                                 // kk tile
        int jt = j - 1;
        int row0 = (jt >> 2) * 64, col0 = (jt & 3) * 64;
        for (int k0 = 0; k0 < 256; k0 += 32) {
            int gk = k0 + cgp * 8;
            int c = col0 + r;
            s8v va = *(const s8v*)(lmXb + (size_t)(row0 + r) * PD + gk);
            s8v vb = (c < 128) ? *(const s8v*)(akwb + (size_t)c * PD + gk)
                               : *(const s8v*)(pkwb + (size_t)(c - 128) * PD + gk);
            *(s8v*)(Als + r * 40 + cgp * 8) = va;
            *(s8v*)(Bls + r * 40 + cgp * 8) = vb;
            __syncthreads();
            s8v af[2], bf[2];
#pragma unroll
            for (int mt = 0; mt < 2; ++mt)
                af[mt] = *(const s8v*)(Als + (wm * 32 + mt * 16 + lm) * 40 + lq * 8);
#pragma unroll
            for (int nt = 0; nt < 2; ++nt)
                bf[nt] = *(const s8v*)(Bls + (wn * 32 + nt * 16 + lm) * 40 + lq * 8);
#pragma unroll
            for (int mt = 0; mt < 2; ++mt)
#pragma unroll
                for (int nt = 0; nt < 2; ++nt)
                    acc[mt][nt] = __builtin_amdgcn_mfma_f32_16x16x32_bf16(
                        af[mt], bf[nt], acc[mt][nt], 0, 0, 0);
            __syncthreads();
        }
#pragma unroll
        for (int mt = 0; mt < 2; ++mt)
#pragma unroll
            for (int nt = 0; nt < 2; ++nt) {
                int c = col0 + wn * 32 + nt * 16 + lm;
                float bv = (c < 128) ? akb[c] : pkb[c - 128];
#pragma unroll
                for (int i = 0; i < 4; ++i) {
                    int rr = row0 + wm * 32 + mt * 16 + lq * 4 + i;
                    kk[(size_t)rr * 256 + c] = f2b(acc[mt][nt][i] + bv);
                }
            }
    } else if (j < 321) {                          // qb tile
        int jt = j - 257;
        int row0 = (jt >> 1) * 64, col0 = (jt & 1) * 64;
        for (int k0 = 0; k0 < 256; k0 += 32) {
            int gk = k0 + cgp * 8;
            s8v va = *(const s8v*)(tgXb + (size_t)(row0 + r) * PD + gk);
            s8v vb = *(const s8v*)(aqwb + (size_t)(col0 + r) * PD + gk);
            *(s8v*)(Als + r * 40 + cgp * 8) = va;
            *(s8v*)(Bls + r * 40 + cgp * 8) = vb;
            __syncthreads();
            s8v af[2], bf[2];
#pragma unroll
            for (int mt = 0; mt < 2; ++mt)
                af[mt] = *(const s8v*)(Als + (wm * 32 + mt * 16 + lm) * 40 + lq * 8);
#pragma unroll
            for (int nt = 0; nt < 2; ++nt)
                bf[nt] = *(const s8v*)(Bls + (wn * 32 + nt * 16 + lm) * 40 + lq * 8);
#pragma unroll
            for (int mt = 0; mt < 2; ++mt)
#pragma unroll
                for (int nt = 0; nt < 2; ++nt)
                    acc[mt][nt] = __builtin_amdgcn_mfma_f32_16x16x32_bf16(
                        af[mt], bf[nt], acc[mt][nt], 0, 0, 0);
            __syncthreads();
        }
        const float INV_TEMP = 0.08838834764831845f;
#pragma unroll
        for (int mt = 0; mt < 2; ++mt)
#pragma unroll
            for (int nt = 0; nt < 2; ++nt) {
                int c = col0 + wn * 32 + nt * 16 + lm;
                float bv = aqb[c];
#pragma unroll
                for (int i = 0; i < 4; ++i) {
                    int rr = row0 + wm * 32 + mt * 16 + lq * 4 + i;
                    qb[(size_t)rr * DZ + c] = f2b(INV_TEMP * (acc[mt][nt][i] + bv));
                }
            }
    } else {                                       // Wc = W2 @ W1 tile
        int jt = j - 321;
        int row0 = (jt / 5) * 64, col0 = (jt % 5) * 64;
        for (int k0 = 0; k0 < PD2P; k0 += 32) {
            int gk = k0 + cgp * 8;
            s8v va = zero8, vb = zero8;
            if (gk < PD2P) {
                int c2 = row0 + r;
                if (c2 < PD2) va = *(const s8v*)(w2wb + (size_t)c2 * PD2P + gk);
                int c1 = col0 + r;
                if (c1 < PD2) vb = *(const s8v*)(w1wtb + (size_t)c1 * PD2P + gk);
            }
            *(s8v*)(Als + r * 40 + cgp * 8) = va;
            *(s8v*)(Bls + r * 40 + cgp * 8) = vb;
            __syncthreads();
            s8v af[2], bf[2];
#pragma unroll
            for (int mt = 0; mt < 2; ++mt)
                af[mt] = *(const s8v*)(Als + (wm * 32 + mt * 16 + lm) * 40 + lq * 8);
#pragma unroll
            for (int nt = 0; nt < 2; ++nt)
                bf[nt] = *(const s8v*)(Bls + (wn * 32 + nt * 16 + lm) * 40 + lq * 8);
#pragma unroll
            for (int mt = 0; mt < 2; ++mt)
#pragma unroll
                for (int nt = 0; nt < 2; ++nt)
                    acc[mt][nt] = __builtin_amdgcn_mfma_f32_16x16x32_bf16(
                        af[mt], bf[nt], acc[mt][nt], 0, 0, 0);
            __syncthreads();
        }
#pragma unroll
        for (int mt = 0; mt < 2; ++mt)
#pragma unroll
            for (int nt = 0; nt < 2; ++nt) {
                int c = col0 + wn * 32 + nt * 16 + lm;
                if (c >= PD2P) continue;
#pragma unroll
                for (int i = 0; i < 4; ++i) {
                    int rr = row0 + wm * 32 + mt * 16 + lq * 4 + i;
                    if (rr < PD2) wcb[(size_t)rr * PD2P + c] = f2b(acc[mt][nt][i]);
                }
            }
    }
}

// ---------------------------------------------------------------- scores1 + exp (+stage C: router1)
// blocks [0,512): GEMM tiles; [512,516): router1 = W1 @ rp0 + b1 (wave-parallel dots)
__global__ __launch_bounds__(256) void scores_e(
    const short* __restrict__ Qb, const short* __restrict__ Kk,
    short* __restrict__ E, float* __restrict__ Z,
    const float* __restrict__ w1w, const float* __restrict__ w1b,
    const float* __restrict__ rp0g, float* __restrict__ router1)
{
    const int j = blockIdx.x, tid = threadIdx.x;
    __shared__ __align__(16) short LDS[10240];     // 2 x 128 x 40
    if (j >= 512) {                                // ---- stage C
        float* rp0s = (float*)LDS;                 // 258 floats
        for (int c = tid; c < PD2; c += 256) rp0s[c] = rp0g[c];
        __syncthreads();
        const int wv = tid >> 6, lane = tid & 63;
        int cstart = (j - 512) * 66;
        int cend = cstart + 66; if (cend > PD2) cend = PD2;
        for (int c = cstart + wv; c < cend; c += 4) {
            const float* wr = w1w + (size_t)c * PD2;
            float p = wr[lane] * rp0s[lane]
                    + wr[64 + lane] * rp0s[64 + lane]
                    + wr[128 + lane] * rp0s[128 + lane]
                    + wr[192 + lane] * rp0s[192 + lane];
            if (lane < 2) p += wr[256 + lane] * rp0s[256 + lane];
#pragma unroll
            for (int msk = 1; msk < 64; msk <<= 1) p += __shfl_xor(p, msk, 64);
            if (lane == 0) router1[c] = p + w1b[c];
        }
        return;
    }
    short* Als = LDS;
    short* Bls = LDS + 128 * 40;
    const int lane = tid & 63, wv = tid >> 6;
    const int wm = wv >> 1, wn = wv & 1;
    const int lm = lane & 15, lq = lane >> 4;
    const int row0 = (j >> 5) * 128, col0 = (j & 31) * 128;
    const f32x4 zero4 = {0.f, 0.f, 0.f, 0.f};
    f32x4 acc[4][4];
#pragma unroll
    for (int mt = 0; mt < 4; ++mt)
#pragma unroll
        for (int nt = 0; nt < 4; ++nt) acc[mt][nt] = zero4;
    for (int k0 = 0; k0 < 128; k0 += 32) {
#pragma unroll
        for (int l = 0; l < 2; ++l) {
            int id = l * 256 + tid;
            int r = id >> 2, cgp = id & 3;
            int gk = k0 + cgp * 8;
            *(s8v*)(Als + r * 40 + cgp * 8) = *(const s8v*)(Qb + (size_t)(row0 + r) * DZ + gk);
            *(s8v*)(Bls + r * 40 + cgp * 8) = *(const s8v*)(Kk + (size_t)(col0 + r) * 256 + gk);
        }
        __syncthreads();
        s8v af[4], bf[4];
#pragma unroll
        for (int mt = 0; mt < 4; ++mt)
            af[mt] = *(const s8v*)(Als + (wm * 64 + mt * 16 + lm) * 40 + lq * 8);
#pragma unroll
        for (int nt = 0; nt < 4; ++nt)
            bf[nt] = *(const s8v*)(Bls + (wn * 64 + nt * 16 + lm) * 40 + lq * 8);
#pragma unroll
        for (int mt = 0; mt < 4; ++mt)
#pragma unroll
            for (int nt = 0; nt < 4; ++nt)
                acc[mt][nt] = __builtin_amdgcn_mfma_f32_16x16x32_bf16(
                    af[mt], bf[nt], acc[mt][nt], 0, 0, 0);
        __syncthreads();
    }
#pragma unroll
    for (int mt = 0; mt < 4; ++mt)
#pragma unroll
        for (int i = 0; i < 4; ++i) {
            int r = row0 + wm * 64 + mt * 16 + lq * 4 + i;
            float rs = 0.f;
#pragma unroll
            for (int nt = 0; nt < 4; ++nt) {
                int c = col0 + wn * 64 + nt * 16 + lm;
                float e = __expf(acc[mt][nt][i]);
                E[(size_t)r * N1 + c] = f2b(e);
                rs += e;
            }
#pragma unroll
            for (int msk = 1; msk < 16; msk <<= 1) rs += __shfl_xor(rs, msk, 64);
            if (lm == 0) atomicAdd(&Z[r], rs);
        }
}

// ---------------------------------------------------------------- AP split-K (+stage D: rr2/u0)
// blocks [0,256): GEMM (128-row, 512 thr — R5-proven); [256,260): rr2/u0 wave dots
__global__ __launch_bounds__(512) void ap_gemm(const short* __restrict__ E,
                                               const float* __restrict__ Z,
                                               const short* __restrict__ lmFTb,
                                               short* __restrict__ part,
                                               const float* __restrict__ w2w,
                                               const float* __restrict__ w1b,
                                               const float* __restrict__ router1,
                                               float* __restrict__ rr2,
                                               float* __restrict__ u0)
{
    __shared__ __align__(16) short LDS[28800];     // 57.6 KB
    const int tid = threadIdx.x, bid = blockIdx.x;
    if (bid >= 256) {                              // ---- stage D
        float* r1s = (float*)LDS;                  // 258
        float* b1s = r1s + 260;                    // 258
        for (int c = tid; c < PD2; c += 512) { r1s[c] = router1[c]; b1s[c] = w1b[c]; }
        __syncthreads();
        const int wv8 = tid >> 6, lane = tid & 63;
        int cstart = (bid - 256) * 66;
        int cend = cstart + 66; if (cend > PD2) cend = PD2;
        for (int c = cstart + wv8; c < cend; c += 8) {
            const float* wr = w2w + (size_t)c * PD2;
            float w0 = wr[lane], w1v = wr[64 + lane], w2v = wr[128 + lane], w3 = wr[192 + lane];
            float pa = w0 * r1s[lane] + w1v * r1s[64 + lane]
                     + w2v * r1s[128 + lane] + w3 * r1s[192 + lane];
            float pb = w0 * b1s[lane] + w1v * b1s[64 + lane]
                     + w2v * b1s[128 + lane] + w3 * b1s[192 + lane];
            if (lane < 2) {
                float w4 = wr[256 + lane];
                pa += w4 * r1s[256 + lane]; pb += w4 * b1s[256 + lane];
            }
#pragma unroll
            for (int msk = 1; msk < 64; msk <<= 1) {
                pa += __shfl_xor(pa, msk, 64);
                pb += __shfl_xor(pb, msk, 64);
            }
            if (lane == 0) { rr2[c] = pa; u0[c] = pb; }
        }
        return;
    }
    const int lane = tid & 63, w8 = tid >> 6;
    const int lm = lane & 15, lq = lane >> 4;
    const int s = bid & 15, row0 = (bid >> 4) * 128;
    const int kbase = s * (N1 / SPLITS);
    short* Als = LDS;
    short* Bls = LDS + 128 * APLD;
    const f32x4 zero4 = {0.f, 0.f, 0.f, 0.f};
    f32x4 acc[17];
#pragma unroll
    for (int nt = 0; nt < 17; ++nt) acc[nt] = zero4;
    for (int it = 0; it < (N1 / SPLITS) / 64; ++it) {
        int k0 = kbase + it * 64;
#pragma unroll
        for (int l = 0; l < 2; ++l) {
            int id = l * 512 + tid;
            int r = id >> 3, gg = id & 7;
            s8v ev = *(const s8v*)(E + (size_t)(row0 + r) * N1 + k0 + gg * 8);
            float invZ = __builtin_amdgcn_rcpf(Z[row0 + r]);
            s8v av;
#pragma unroll
            for (int q = 0; q < 8; ++q)
                av[q] = f2b(__expf(sb2f(ev[q]) * invZ));
            *(s8v*)(Als + r * APLD + gg * 8) = av;
        }
#pragma unroll
        for (int l = 0; l < 5; ++l) {
            int id = l * 512 + tid;
            if (id < APN * 8) {
                int r = id >> 3, gg = id & 7;
                *(s8v*)(Bls + r * APLD + gg * 8) =
                    *(const s8v*)(lmFTb + (size_t)r * N1 + k0 + gg * 8);
            }
        }
        __syncthreads();
        s8v a0 = *(const s8v*)(Als + (w8 * 16 + lm) * APLD + lq * 8);
        s8v a1 = *(const s8v*)(Als + (w8 * 16 + lm) * APLD + 32 + lq * 8);
#pragma unroll
        for (int nt = 0; nt < 17; ++nt) {
            s8v b0 = *(const s8v*)(Bls + (nt * 16 + lm) * APLD + lq * 8);
            s8v b1 = *(const s8v*)(Bls + (nt * 16 + lm) * APLD + 32 + lq * 8);
            acc[nt] = __builtin_amdgcn_mfma_f32_16x16x32_bf16(a0, b0, acc[nt], 0, 0, 0);
            acc[nt] = __builtin_amdgcn_mfma_f32_16x16x32_bf16(a1, b1, acc[nt], 0, 0, 0);
        }
        __syncthreads();
    }
    short* op = part + (size_t)s * N2 * APN;
#pragma unroll
    for (int nt = 0; nt < 17; ++nt) {
        int c = nt * 16 + lm;
#pragma unroll
        for (int i = 0; i < 4; ++i) {
            int r = row0 + w8 * 16 + lq * 4 + i;
            op[(size_t)r * APN + c] = f2b(acc[nt][i]);
        }
    }
}

// ---------------------------------------------------------------- tgp0 reduce+fixup
__global__ __launch_bounds__(256) void fix_tgp0(const short* __restrict__ part,
                                                const float* __restrict__ tgX,
                                                const float* __restrict__ rou0,
                                                const float* __restrict__ router0,
                                                short* __restrict__ outb) {
    int r = blockIdx.x;
    int tid = threadIdx.x;
    __shared__ float sAsum;
    float s0 = 0.f, s1 = 0.f;
#pragma unroll
    for (int s = 0; s < SPLITS; ++s)
        s0 += sb2f(part[((size_t)s * N2 + r) * APN + tid]);
    if (tid < 8) {
#pragma unroll
        for (int s = 0; s < SPLITS; ++s)
            s1 += sb2f(part[((size_t)s * N2 + r) * APN + 256 + tid]);
    }
    if (tid == 2) sAsum = s1;   // col 258
    __syncthreads();
    float ro = rou0[r];
    float inv = 1.f / (1.f + sAsum + ro + 1e-12f);
    {
        float v = (s0 + tgX[(size_t)r * PD + tid] + ro * router0[tid]) * inv;
        outb[(size_t)r * PD2P + tid] = f2b(v);
    }
    if (tid < 8) {
        int c = 256 + tid;
        float v = 0.f;
        if (c < PD2) v = (s1 + ro * router0[c]) * inv;
        outb[(size_t)r * PD2P + c] = f2b(v);
    }
}

// ---------------------------------------------------------------- fused W1/W2 layer GEMM
// grid (10, 32): x<5 -> tf1 = tgp0@W1^T + b1 (cols 256..513)
//                x>=5 -> tf2 = (tgp0@Wc^T + u0 + rou1*rr2)/(1+rou1) + b2 (cols 514..771)
__global__ __launch_bounds__(256) void w12_gemm(
    const short* __restrict__ A, const short* __restrict__ B1,
    const short* __restrict__ B2,
    const float* __restrict__ b1, const float* __restrict__ b2,
    const float* __restrict__ rou1, const float* __restrict__ rr2,
    const float* __restrict__ u0,
    float* __restrict__ outF, short* __restrict__ finalFb)
{
    __shared__ __align__(16) short LDS[5120];
    short* Als = LDS;
    short* Bls = LDS + 64 * 40;
    const int tid = threadIdx.x;
    const int lane = tid & 63, wv = tid >> 6;
    const int wm = wv >> 1, wn = wv & 1;
    const int lm = lane & 15, lq = lane >> 4;
    const int bx = blockIdx.x;
    const int mode2 = bx >= 5;
    const int col0 = (mode2 ? bx - 5 : bx) * 64;
    const short* B = mode2 ? B2 : B1;
    const int row0 = blockIdx.y * 64;
    const f32x4 zero4 = {0.f, 0.f, 0.f, 0.f};
    f32x4 acc[2][2] = {{zero4, zero4}, {zero4, zero4}};
    const s8v zero8 = {0, 0, 0, 0, 0, 0, 0, 0};
    const int r = tid >> 2, cgp = tid & 3;
    for (int k0 = 0; k0 < PD2P; k0 += 32) {
        int gk = k0 + cgp * 8;
        s8v va = zero8, vb = zero8;
        if (gk < PD2P) {
            va = *(const s8v*)(A + (size_t)(row0 + r) * PD2P + gk);
            if (col0 + r < PD2) vb = *(const s8v*)(B + (size_t)(col0 + r) * PD2P + gk);
        }
        *(s8v*)(Als + r * 40 + cgp * 8) = va;
        *(s8v*)(Bls + r * 40 + cgp * 8) = vb;
        __syncthreads();
        s8v af[2], bf[2];
#pragma unroll
        for (int mt = 0; mt < 2; ++mt)
            af[mt] = *(const s8v*)(Als + (wm * 32 + mt * 16 + lm) * 40 + lq * 8);
#pragma unroll
        for (int nt = 0; nt < 2; ++nt)
            bf[nt] = *(const s8v*)(Bls + (wn * 32 + nt * 16 + lm) * 40 + lq * 8);
#pragma unroll
        for (int mt = 0; mt < 2; ++mt)
#pragma unroll
            for (int nt = 0; nt < 2; ++nt)
                acc[mt][nt] = __builtin_amdgcn_mfma_f32_16x16x32_bf16(
                    af[mt], bf[nt], acc[mt][nt], 0, 0, 0);
        __syncthreads();
    }
#pragma unroll
    for (int mt = 0; mt < 2; ++mt)
#pragma unroll
        for (int nt = 0; nt < 2; ++nt) {
            int c = col0 + wn * 32 + nt * 16 + lm;
            if (c >= PD2) continue;
#pragma unroll
            for (int i = 0; i < 4; ++i) {
                int rr = row0 + wm * 32 + mt * 16 + lq * 4 + i;
                float v;
                int co;
                if (!mode2) {
                    v = acc[mt][nt][i] + b1[c];
                    co = 256 + c;
                } else {
                    float ro = rou1[rr];
                    float invd = 1.f / (1.f + ro + 1e-12f);
                    v = (acc[mt][nt][i] + u0[c] + ro * rr2[c]) * invd + b2[c];
                    co = 514 + c;
                }
                outF[(size_t)rr * FD + co] = v;
                finalFb[(size_t)rr * FDP + co] = f2b(v);
            }
        }
}

// ---------------------------------------------------------------- q2 projection (K=776)
__global__ __launch_bounds__(256) void q2_gemm(
    const short* __restrict__ A, const short* __restrict__ B,
    const float* __restrict__ bias, short* __restrict__ outB)
{
    __shared__ __align__(16) short LDS[5120];
    short* Als = LDS;
    short* Bls = LDS + 64 * 40;
    const int tid = threadIdx.x;
    const int lane = tid & 63, wv = tid >> 6;
    const int wm = wv >> 1, wn = wv & 1;
    const int lm = lane & 15, lq = lane >> 4;
    const int row0 = blockIdx.y * 64, col0 = blockIdx.x * 64;
    const f32x4 zero4 = {0.f, 0.f, 0.f, 0.f};
    f32x4 acc[2][2] = {{zero4, zero4}, {zero4, zero4}};
    const s8v zero8 = {0, 0, 0, 0, 0, 0, 0, 0};
    const int r = tid >> 2, cgp = tid & 3;
    for (int k0 = 0; k0 < FDP; k0 += 32) {
        int gk = k0 + cgp * 8;
        s8v va = zero8, vb = zero8;
        if (gk < FDP) {
            va = *(const s8v*)(A + (size_t)(row0 + r) * FDP + gk);
            vb = *(const s8v*)(B + (size_t)(col0 + r) * FDP + gk);
        }
        *(s8v*)(Als + r * 40 + cgp * 8) = va;
        *(s8v*)(Bls + r * 40 + cgp * 8) = vb;
        __syncthreads();
        s8v af[2], bf[2];
#pragma unroll
        for (int mt = 0; mt < 2; ++mt)
            af[mt] = *(const s8v*)(Als + (wm * 32 + mt * 16 + lm) * 40 + lq * 8);
#pragma unroll
        for (int nt = 0; nt < 2; ++nt)
            bf[nt] = *(const s8v*)(Bls + (wn * 32 + nt * 16 + lm) * 40 + lq * 8);
#pragma unroll
        for (int mt = 0; mt < 2; ++mt)
#pragma unroll
            for (int nt = 0; nt < 2; ++nt)
                acc[mt][nt] = __builtin_amdgcn_mfma_f32_16x16x32_bf16(
                    af[mt], bf[nt], acc[mt][nt], 0, 0, 0);
        __syncthreads();
    }
    const float INV_TEMP = 0.08838834764831845f;
#pragma unroll
    for (int mt = 0; mt < 2; ++mt)
#pragma unroll
        for (int nt = 0; nt < 2; ++nt) {
            int c = col0 + wn * 32 + nt * 16 + lm;
            float bv = bias[c];
#pragma unroll
            for (int i = 0; i < 4; ++i) {
                int rr = row0 + wm * 32 + mt * 16 + lq * 4 + i;
                outB[(size_t)rr * DZ + c] = f2b(INV_TEMP * (acc[mt][nt][i] + bv));
            }
        }
}

// ---------------------------------------------------------------- attention 2
// 512 blocks: chunk (16 x 256 cols) x rowblock (32 x 64 rows).
// R5-proven: LDS-staged K, per-lane accumulation across tiles, single
// end-of-kernel butterfly, plain part2 stores + separate combine.
__global__ __launch_bounds__(256) void attn2_flash(
    const short* __restrict__ Q, const short* __restrict__ Kk,
    const float* __restrict__ V, float* __restrict__ part2)
{
    __shared__ __align__(16) short Qls[64 * 136];
    __shared__ __align__(16) short Kls[64 * 136];
    __shared__ float Vls[128];
    const int tid = threadIdx.x;
    const int lane = tid & 63, wv = tid >> 6;
    const int lm = lane & 15, lq = lane >> 4;
    const int chunk = blockIdx.x & 15, row0 = (blockIdx.x >> 4) * 64;
    const f32x4 zero4 = {0.f, 0.f, 0.f, 0.f};
#pragma unroll
    for (int l = 0; l < 4; ++l) {
        int id = l * 256 + tid;
        int r = id >> 4, g = id & 15;
        *(s8v*)(Qls + r * 136 + g * 8) = *(const s8v*)(Q + (size_t)(row0 + r) * DZ + g * 8);
    }
    __syncthreads();
    s8v af[4];
#pragma unroll
    for (int ks = 0; ks < 4; ++ks)
        af[ks] = *(const s8v*)(Qls + (wv * 16 + lm) * 136 + ks * 32 + lq * 8);
    float z[4] = {0.f, 0.f, 0.f, 0.f};
    float y0[4] = {0.f, 0.f, 0.f, 0.f};
    float y1[4] = {0.f, 0.f, 0.f, 0.f};
    for (int t = 0; t < 4; ++t) {
        int col0 = chunk * 256 + t * 64;
        __syncthreads();
#pragma unroll
        for (int l = 0; l < 4; ++l) {
            int id = l * 256 + tid;
            int r = id >> 4, g = id & 15;
            *(s8v*)(Kls + r * 136 + g * 8) =
                *(const s8v*)(Kk + (size_t)(col0 + r) * 256 + 128 + g * 8);
        }
        if (tid < 128) Vls[tid] = V[col0 * 2 + tid];
        __syncthreads();
        f32x4 acc[4];
#pragma unroll
        for (int nt = 0; nt < 4; ++nt) acc[nt] = zero4;
#pragma unroll
        for (int nt = 0; nt < 4; ++nt)
#pragma unroll
            for (int ks = 0; ks < 4; ++ks) {
                s8v bf = *(const s8v*)(Kls + (nt * 16 + lm) * 136 + ks * 32 + lq * 8);
                acc[nt] = __builtin_amdgcn_mfma_f32_16x16x32_bf16(af[ks], bf, acc[nt], 0, 0, 0);
            }
        float v0[4], v1[4];
#pragma unroll
        for (int nt = 0; nt < 4; ++nt) {
            v0[nt] = Vls[(nt * 16 + lm) * 2];
            v1[nt] = Vls[(nt * 16 + lm) * 2 + 1];
        }
        // per-lane accumulation: NO cross-lane ops inside the tile loop
#pragma unroll
        for (int i = 0; i < 4; ++i) {
            float e0 = __expf(acc[0][i]), e1 = __expf(acc[1][i]);
            float e2 = __expf(acc[2][i]), e3 = __expf(acc[3][i]);
            z[i]  += e0 + e1 + e2 + e3;
            y0[i] += e0 * v0[0] + e1 * v0[1] + e2 * v0[2] + e3 * v0[3];
            y1[i] += e0 * v1[0] + e1 * v1[1] + e2 * v1[2] + e3 * v1[3];
        }
    }
    // single end-of-kernel butterfly over the 16 column-lanes
#pragma unroll
    for (int i = 0; i < 4; ++i) {
#pragma unroll
        for (int msk = 1; msk < 16; msk <<= 1) {
            z[i]  += __shfl_xor(z[i], msk, 64);
            y0[i] += __shfl_xor(y0[i], msk, 64);
            y1[i] += __shfl_xor(y1[i], msk, 64);
        }
    }
    if (lm == 0) {
#pragma unroll
        for (int i = 0; i < 4; ++i) {
            int r = row0 + wv * 16 + lq * 4 + i;
            float* pp = part2 + ((size_t)r * 16 + chunk) * 4;
            pp[0] = z[i]; pp[1] = y0[i]; pp[2] = y1[i];
        }
    }
}

__global__ void attn2_combine(const float* __restrict__ part2, float* __restrict__ out) {
    int r = blockIdx.x * 256 + threadIdx.x;
    if (r >= N2) return;
    const float* pp = part2 + (size_t)r * 64;
    float Zt = 0.f, Y0 = 0.f, Y1 = 0.f;
#pragma unroll
    for (int c = 0; c < 16; ++c) {
        Zt += pp[c * 4]; Y0 += pp[c * 4 + 1]; Y1 += pp[c * 4 + 2];
    }
    out[2 * r] = Y0 / Zt;
    out[2 * r + 1] = Y1 / Zt;
}

// ---------------------------------------------------------------- launch
extern "C" void kernel_launch(void* const* d_in, const int* in_sizes, int n_in,
                              void* d_out, int out_size, void* d_ws, size_t ws_size,
                              hipStream_t stream) {
    const float* lm_X = (const float*)d_in[0];
    const float* lm_Y = (const float*)d_in[1];
    const float* tg_X = (const float*)d_in[2];
    const float* lm_delay = (const float*)d_in[4];
    const float* tg_delay = (const float*)d_in[5];
    const float* aq_w = (const float*)d_in[6];
    const float* aq_b = (const float*)d_in[7];
    const float* ak_w = (const float*)d_in[8];
    const float* ak_b = (const float*)d_in[9];
    const float* w1_w = (const float*)d_in[10];
    const float* w1_b = (const float*)d_in[11];
    const float* w2_w = (const float*)d_in[12];
    const float* w2_b = (const float*)d_in[13];
    const float* pq_w = (const float*)d_in[14];
    const float* pq_b = (const float*)d_in[15];
    const float* pk_w = (const float*)d_in[16];
    const float* pk_b = (const float*)d_in[17];
    const float* pv_w = (const float*)d_in[18];
    const float* pv_b = (const float*)d_in[19];
    const float* g1 = (const float*)d_in[20];
    const float* g2 = (const float*)d_in[21];
    const float* g3 = (const float*)d_in[22];
    const float* al = (const float*)d_in[23];
    const float* be = (const float*)d_in[24];

    float* out = (float*)d_out;
    float* outF = out + (size_t)N2 * 2;

    char* base = (char*)d_ws;
    size_t off = 0;
    auto allocF = [&](size_t n) -> float* {
        float* q = (float*)(base + off);
        off += (n * 4 + 255) / 256 * 256;
        return q;
    };
    auto allocS = [&](size_t n) -> short* {
        short* q = (short*)(base + off);
        off += (n * 2 + 255) / 256 * 256;
        return q;
    };

    short* E        = allocS((size_t)N2 * N1);
    short* appart   = allocS((size_t)SPLITS * N2 * APN);
    short* lmFTb    = allocS((size_t)APN * N1);
    short* lmXb     = allocS((size_t)N1 * PD);
    short* tgXb     = allocS((size_t)N2 * PD);
    short* qbuf     = allocS((size_t)N2 * DZ);
    short* kk       = allocS((size_t)N1 * 256);
    short* q2       = allocS((size_t)N2 * DZ);
    short* tgp0b    = allocS((size_t)N2 * PD2P);
    short* finalFb  = allocS((size_t)N2 * FDP);
    short* w1wb     = allocS((size_t)PD2 * PD2P);
    short* w2wb     = allocS((size_t)PD2 * PD2P);
    short* w1wtb    = allocS((size_t)PD2 * PD2P);
    short* wcb      = allocS((size_t)PD2 * PD2P);
    short* pqwb     = allocS((size_t)DZ * FDP);
    short* aqwb     = allocS((size_t)DZ * PD);
    short* akwb     = allocS((size_t)DZ * PD);
    short* pkwb     = allocS((size_t)DZ * PD);
    float* v2b      = allocF((size_t)N1 * 2);
    float* part2    = allocF((size_t)N2 * 64);
    float* Zbuf     = allocF(N2);
    float* router0  = allocF(PD2);
    float* rp0g     = allocF(PD2);
    float* router1  = allocF(PD2);
    float* rr2v     = allocF(PD2);
    float* u0v      = allocF(PD2);
    float* r1part   = allocF(64 * 256);
    float* r2part   = allocF(64 * 256);
    float* rou0     = allocF(N2);
    float* rou1     = allocF(N2);

    // 1. transpose + conversions + zero-fills (+ router partial sums)
    hipLaunchKernelGGL(cvt_all, dim3(CVT_GRID), dim3(256), 0, stream,
                       lm_X, lm_Y, tg_X, aq_w, ak_w, pk_w, pq_w, w1_w, w2_w,
                       lm_delay, tg_delay, g1, g2, g3, al, be, pv_w, pv_b,
                       w1wb, w2wb, w1wtb, pqwb, aqwb, akwb, pkwb,
                       lmXb, tgXb, lmFTb, rou0, rou1, v2b, Zbuf,
                       finalFb, outF, r1part, r2part);
    // 2. stage B (block 0) + kk + qb + Wc
    hipLaunchKernelGGL(rkq_kernel, dim3(346), dim3(256), 0, stream,
                       lmXb, tgXb, aqwb, akwb, pkwb, aq_b, ak_b, pk_b,
                       w2wb, w1wtb, r1part, r2part, lm_Y, lm_delay,
                       g1, al, be, kk, qbuf, wcb, router0, rp0g);
    // 3. E = exp(scores), Z rowsums (+stage C: router1, 4 blocks)
    hipLaunchKernelGGL(scores_e, dim3(516), dim3(256), 0, stream,
                       qbuf, kk, E, Zbuf, w1_w, w1_b, rp0g, router1);
    // 4. AP partials, 128-row tiles (+stage D: rr2/u0, 4 blocks)
    hipLaunchKernelGGL(ap_gemm, dim3(260), dim3(512), 0, stream,
                       E, Zbuf, lmFTb, appart, w2_w, w1_b, router1, rr2v, u0v);
    // 5. tgp0
    hipLaunchKernelGGL(fix_tgp0, dim3(N2), dim3(256), 0, stream,
                       appart, tg_X, rou0, router0, tgp0b);
    // 6. tf1 + tf2 in parallel (Wc reassociation)
    hipLaunchKernelGGL(w12_gemm, dim3(10, 32), dim3(256), 0, stream,
                       tgp0b, w1wb, wcb, w1_b, w2_b, rou1, rr2v, u0v,
                       outF, finalFb);
    // 7. q2
    hipLaunchKernelGGL(q2_gemm, dim3(2, 32), dim3(256), 0, stream,
                       finalFb, pqwb, pq_b, q2);
    // 8-9. attention 2 (R5 LDS-staged) + combine (no atomics)
    hipLaunchKernelGGL(attn2_flash, dim3(512), dim3(256), 0, stream,
                       q2, kk, v2b, part2);
    hipLaunchKernelGGL(attn2_combine, dim3(8), dim3(256), 0, stream, part2, out);
}